// Round 1
// baseline (409.741 us; speedup 1.0000x reference)
//
#include <hip/hip_runtime.h>
#include <hip/hip_bf16.h>
#include <stdint.h>

#define B_ 4
#define S_ 4096
#define E_ 1024
#define H_ 16
#define D_ 64
#define M_ (B_*S_)          // 16384 rows
constexpr float kEPS = 1e-6f;

typedef unsigned short u16;
typedef unsigned char  u8;
typedef __bf16 bf16x8 __attribute__((ext_vector_type(8)));
typedef float  f32x4  __attribute__((ext_vector_type(4)));
typedef u16    u16x8  __attribute__((ext_vector_type(8)));

typedef const __attribute__((address_space(1))) void* gaddr_t;
typedef __attribute__((address_space(3))) void*       laddr_t;

__device__ __forceinline__ u16 f2bf(float f) {
    union { float f; uint32_t u; } v; v.f = f;
    uint32_t u = v.u;
    u += 0x7fffu + ((u >> 16) & 1u);   // RNE
    return (u16)(u >> 16);
}
__device__ __forceinline__ float bf2f(u16 h) {
    union { uint32_t u; float f; } v; v.u = ((uint32_t)h) << 16;
    return v.f;
}

// ---------------- f32 -> bf16 conversion, 4-wide ----------------
__global__ void cvt_kernel(const float* __restrict__ in, u16* __restrict__ out, int n4) {
    int i = blockIdx.x * blockDim.x + threadIdx.x;
    if (i >= n4) return;
    float4 v = reinterpret_cast<const float4*>(in)[i];
    ushort4 o;
    o.x = f2bf(v.x); o.y = f2bf(v.y); o.z = f2bf(v.z); o.w = f2bf(v.w);
    reinterpret_cast<ushort4*>(out)[i] = o;
}

// ---------------- bf16 GEMM, C = A @ B^T (+bias, epilogue) ----------------
// A: [M][K] bf16 row-major. Bw: [N][K] bf16 row-major (i.e. weight W, C[m,n]=sum_k A[m,k]*W[n,k]).
// EPI: 0 = f32 out (bias)            -> Cf
//      1 = bf16 out relu(x+b)+eps    -> Cb
//      2 = EPI1 then zero where mask -> Cb
//      3 = bf16 out x+b              -> Cb
#define BM 128
#define BN 128
#define BK 32

template<int EPI>
__global__ __launch_bounds__(256)
void gemm_bt(const u16* __restrict__ A, const u16* __restrict__ Bw,
             const float* __restrict__ bias, const u8* __restrict__ mask,
             float* __restrict__ Cf, u16* __restrict__ Cb,
             int M, int N, int K)
{
    __shared__ u16 As[BM*BK];   // 8 KB
    __shared__ u16 Bs[BN*BK];   // 8 KB
    const int tid  = threadIdx.x;
    const int wid  = tid >> 6, lane = tid & 63;
    const int wr   = wid >> 1, wc = wid & 1;
    const int n0   = blockIdx.x * BN;   // x = n-tile (8) so consecutive blocks share A-panel
    const int m0   = blockIdx.y * BM;

    const int srow = lane >> 2;          // staging row within 16-row group
    const int skc  = (lane & 3) * 8;     // staging k element offset (16B chunks)
    const int fr   = lane & 15;          // fragment row
    const int fk   = (lane >> 4) * 8;    // fragment k offset

    f32x4 acc[4][4] = {};

    float bias_v[4];
#pragma unroll
    for (int j = 0; j < 4; ++j) bias_v[j] = bias[n0 + wc*64 + j*16 + fr];

    for (int kt = 0; kt < K; kt += BK) {
#pragma unroll
        for (int p = 0; p < 2; ++p) {
            const int row0 = p*64 + wid*16;   // wave-uniform
            const u16* ag = A  + (size_t)(m0 + row0 + srow)*K + kt + skc;
            const u16* bg = Bw + (size_t)(n0 + row0 + srow)*K + kt + skc;
            __builtin_amdgcn_global_load_lds((gaddr_t)ag, (laddr_t)(As + row0*BK), 16, 0, 0);
            __builtin_amdgcn_global_load_lds((gaddr_t)bg, (laddr_t)(Bs + row0*BK), 16, 0, 0);
        }
        __syncthreads();

        bf16x8 af[4], bfv[4];
#pragma unroll
        for (int i = 0; i < 4; ++i) {
            af[i]  = *reinterpret_cast<const bf16x8*>(As + (wr*64 + i*16 + fr)*BK + fk);
            bfv[i] = *reinterpret_cast<const bf16x8*>(Bs + (wc*64 + i*16 + fr)*BK + fk);
        }
#pragma unroll
        for (int i = 0; i < 4; ++i)
#pragma unroll
            for (int j = 0; j < 4; ++j)
                acc[i][j] = __builtin_amdgcn_mfma_f32_16x16x32_bf16(af[i], bfv[j], acc[i][j], 0, 0, 0);
        __syncthreads();
    }

    const int l4 = lane >> 4;
#pragma unroll
    for (int i = 0; i < 4; ++i) {
#pragma unroll
        for (int j = 0; j < 4; ++j) {
            const int gn = n0 + wc*64 + j*16 + fr;
#pragma unroll
            for (int r = 0; r < 4; ++r) {
                const int gm = m0 + wr*64 + i*16 + l4*4 + r;
                float x = acc[i][j][r] + bias_v[j];
                if (EPI == 0) {
                    Cf[(size_t)gm*N + gn] = x;
                } else if (EPI == 1) {
                    x = fmaxf(x, 0.f) + kEPS;
                    Cb[(size_t)gm*N + gn] = f2bf(x);
                } else if (EPI == 2) {
                    x = fmaxf(x, 0.f) + kEPS;
                    if (mask[gm]) x = 0.f;
                    Cb[(size_t)gm*N + gn] = f2bf(x);
                } else {
                    Cb[(size_t)gm*N + gn] = f2bf(x);
                }
            }
        }
    }
}

// ---------------- stage 2: kv partial = K_chunk^T @ V_chunk, ksum partial ----------------
#define SC 128
#define NCHUNK (S_/SC)   // 32
__global__ __launch_bounds__(256)
void kv_partial_kernel(const u16* __restrict__ Ka, const u16* __restrict__ Vv,
                       float* __restrict__ kvp, float* __restrict__ ksp)
{
    __shared__ u16   Ks[SC*64];   // 16 KB
    __shared__ float Vs[SC*64];   // 32 KB
    const int bh = blockIdx.x, b = bh >> 4, h = bh & 15;
    const int s0 = blockIdx.y * SC;
    const int tid = threadIdx.x;

    for (int g = tid; g < SC*8; g += 256) {     // 1024 16B-groups
        int row = g >> 3, c8 = (g & 7) * 8;
        size_t goff = (size_t)(b*S_ + s0 + row)*E_ + h*64 + c8;
        *reinterpret_cast<uint4*>(Ks + row*64 + c8) = *reinterpret_cast<const uint4*>(Ka + goff);
        bf16x8 vv = *reinterpret_cast<const bf16x8*>(Vv + goff);
        f32x4 f0, f1;
#pragma unroll
        for (int j = 0; j < 4; ++j) { f0[j] = (float)vv[j]; f1[j] = (float)vv[4+j]; }
        *reinterpret_cast<f32x4*>(Vs + row*64 + c8)     = f0;
        *reinterpret_cast<f32x4*>(Vs + row*64 + c8 + 4) = f1;
    }
    __syncthreads();

    const int d  = tid >> 2;
    const int v0 = (tid & 3) * 16;
    float acc[16] = {};
    float ks = 0.f;
#pragma unroll 2
    for (int s = 0; s < SC; ++s) {
        float kval = bf2f(Ks[s*64 + d]);
        ks += kval;
        const float* vr = Vs + s*64 + v0;
        f32x4 a0 = *reinterpret_cast<const f32x4*>(vr);
        f32x4 a1 = *reinterpret_cast<const f32x4*>(vr + 4);
        f32x4 a2 = *reinterpret_cast<const f32x4*>(vr + 8);
        f32x4 a3 = *reinterpret_cast<const f32x4*>(vr + 12);
#pragma unroll
        for (int j = 0; j < 4; ++j) {
            acc[j]    += kval * a0[j];
            acc[4+j]  += kval * a1[j];
            acc[8+j]  += kval * a2[j];
            acc[12+j] += kval * a3[j];
        }
    }
    float* dst = kvp + ((size_t)(blockIdx.y*64 + bh)*4096) + d*64 + v0;
#pragma unroll
    for (int j = 0; j < 16; ++j) dst[j] = acc[j];
    if ((tid & 3) == 0) ksp[(size_t)(blockIdx.y*64 + bh)*64 + d] = ks;
}

// ---------------- stage 2b: reduce partials ----------------
__global__ void kv_reduce_kernel(const float* __restrict__ kvp, const float* __restrict__ ksp,
                                 float* __restrict__ kv, float* __restrict__ ksum)
{
    int i = blockIdx.x*256 + threadIdx.x;   // 262144 kv elements
    float s = 0.f;
#pragma unroll
    for (int c = 0; c < NCHUNK; ++c) s += kvp[(size_t)c*262144 + i];
    kv[i] = s;
    if (i < 4096) {
        float t = 0.f;
#pragma unroll
        for (int c = 0; c < NCHUNK; ++c) t += ksp[(size_t)c*4096 + i];
        ksum[i] = t;
    }
}

// ---------------- stage 3: attn = (Qa @ kv) / max(Qa . ksum, eps) ----------------
__global__ __launch_bounds__(256)
void attn_kernel(const u16* __restrict__ Qa, const float* __restrict__ kv,
                 const float* __restrict__ ksum, u16* __restrict__ attn)
{
    __shared__ float kvs[64*64];   // 16 KB
    __shared__ float kss[64];
    const int bh = blockIdx.x, b = bh >> 4, h = bh & 15;
    const int tid = threadIdx.x;
    for (int i = tid; i < 1024; i += 256)
        reinterpret_cast<float4*>(kvs)[i] = reinterpret_cast<const float4*>(kv + (size_t)bh*4096)[i];
    if (tid < 64) kss[tid] = ksum[(size_t)bh*64 + tid];
    __syncthreads();

    const int r  = tid >> 2;             // row within 64-row chunk
    const int v0 = (tid & 3) * 16;
    const int s  = blockIdx.y*64 + r;
    const u16* qrow = Qa + (size_t)(b*S_ + s)*E_ + h*64;

    bf16x8 qv[8];
#pragma unroll
    for (int g = 0; g < 8; ++g) qv[g] = reinterpret_cast<const bf16x8*>(qrow)[g];

    float denom = 0.f;
#pragma unroll
    for (int g = 0; g < 8; ++g)
#pragma unroll
        for (int j = 0; j < 8; ++j) denom += (float)qv[g][j] * kss[g*8 + j];
    denom = fmaxf(denom, kEPS);
    const float inv = 1.0f / denom;

    float acc[16] = {};
#pragma unroll
    for (int g = 0; g < 8; ++g) {
#pragma unroll
        for (int j = 0; j < 8; ++j) {
            const int d = g*8 + j;
            const float qd = (float)qv[g][j];
            const float* kr = kvs + d*64 + v0;
            f32x4 a0 = *reinterpret_cast<const f32x4*>(kr);
            f32x4 a1 = *reinterpret_cast<const f32x4*>(kr + 4);
            f32x4 a2 = *reinterpret_cast<const f32x4*>(kr + 8);
            f32x4 a3 = *reinterpret_cast<const f32x4*>(kr + 12);
#pragma unroll
            for (int v = 0; v < 4; ++v) {
                acc[v]    += qd * a0[v];
                acc[4+v]  += qd * a1[v];
                acc[8+v]  += qd * a2[v];
                acc[12+v] += qd * a3[v];
            }
        }
    }
    u16x8 o0, o1;
#pragma unroll
    for (int j = 0; j < 8; ++j) { o0[j] = f2bf(acc[j]*inv); o1[j] = f2bf(acc[8+j]*inv); }
    u16* orow = attn + (size_t)(b*S_ + s)*E_ + h*64 + v0;
    *reinterpret_cast<u16x8*>(orow)     = o0;
    *reinterpret_cast<u16x8*>(orow + 8) = o1;
}

// ---------------- host ----------------
extern "C" void kernel_launch(void* const* d_in, const int* in_sizes, int n_in,
                              void* d_out, int out_size, void* d_ws, size_t ws_size,
                              hipStream_t stream)
{
    const float* query = (const float*)d_in[0];
    const float* key   = (const float*)d_in[1];
    const float* value = (const float*)d_in[2];
    const u8*    mask  = (const u8*)d_in[3];
    const float* Wq = (const float*)d_in[4];
    const float* bq = (const float*)d_in[5];
    const float* Wk = (const float*)d_in[6];
    const float* bk = (const float*)d_in[7];
    const float* Wv = (const float*)d_in[8];
    const float* bv = (const float*)d_in[9];
    const float* Wo = (const float*)d_in[10];
    const float* bo = (const float*)d_in[11];
    float* out = (float*)d_out;

    const size_t SZ_ME = (size_t)M_ * E_;    // 16,777,216
    const size_t SZ_EE = (size_t)E_ * E_;    // 1,048,576

    char* ws = (char*)d_ws;
    u16* qx  = (u16*)ws; ws += SZ_ME*2;   // query bf16; reused later for attn
    u16* kx  = (u16*)ws; ws += SZ_ME*2;   // key   bf16; reused later for kv partials (32 MiB)
    u16* vx  = (u16*)ws; ws += SZ_ME*2;   // value bf16; reused later for ksp/kv/ksum
    u16* Qa  = (u16*)ws; ws += SZ_ME*2;
    u16* Ka  = (u16*)ws; ws += SZ_ME*2;
    u16* Vv  = (u16*)ws; ws += SZ_ME*2;
    u16* wqb = (u16*)ws; ws += SZ_EE*2;
    u16* wkb = (u16*)ws; ws += SZ_EE*2;
    u16* wvb = (u16*)ws; ws += SZ_EE*2;
    u16* wob = (u16*)ws; ws += SZ_EE*2;

    // overlays (regions free by the time these are written)
    float* kvp  = (float*)kx;                        // 32 chunks * 64 bh * 4096 f32 = 32 MiB
    float* ksp  = (float*)vx;                        // 32*4096 f32 = 512 KiB
    float* kv   = (float*)vx + (size_t)NCHUNK*4096;  // 262144 f32 = 1 MiB
    float* ksum = kv + 262144;                       // 4096 f32
    u16*   attn = qx;

    // 1) conversions to bf16
    cvt_kernel<<<(int)(SZ_ME/4/256), 256, 0, stream>>>(query, qx, (int)(SZ_ME/4));
    cvt_kernel<<<(int)(SZ_ME/4/256), 256, 0, stream>>>(key,   kx, (int)(SZ_ME/4));
    cvt_kernel<<<(int)(SZ_ME/4/256), 256, 0, stream>>>(value, vx, (int)(SZ_ME/4));
    cvt_kernel<<<(int)(SZ_EE/4/256), 256, 0, stream>>>(Wq, wqb, (int)(SZ_EE/4));
    cvt_kernel<<<(int)(SZ_EE/4/256), 256, 0, stream>>>(Wk, wkb, (int)(SZ_EE/4));
    cvt_kernel<<<(int)(SZ_EE/4/256), 256, 0, stream>>>(Wv, wvb, (int)(SZ_EE/4));
    cvt_kernel<<<(int)(SZ_EE/4/256), 256, 0, stream>>>(Wo, wob, (int)(SZ_EE/4));

    // 2) QKV projections (fused epilogues)
    dim3 ggrid(E_/BN, M_/BM);   // (8, 128): consecutive blocks share the A row-panel
    gemm_bt<1><<<ggrid, 256, 0, stream>>>(qx, wqb, bq, nullptr, nullptr, Qa, M_, E_, E_);
    gemm_bt<2><<<ggrid, 256, 0, stream>>>(kx, wkb, bk, mask,    nullptr, Ka, M_, E_, E_);
    gemm_bt<3><<<ggrid, 256, 0, stream>>>(vx, wvb, bv, nullptr, nullptr, Vv, M_, E_, E_);

    // 3) kv_context + k_sum (two-phase, deterministic)
    kv_partial_kernel<<<dim3(B_*H_, NCHUNK), 256, 0, stream>>>(Ka, Vv, kvp, ksp);
    kv_reduce_kernel<<<1024, 256, 0, stream>>>(kvp, ksp, kv, ksum);

    // 4) attn numerator / denom
    attn_kernel<<<dim3(B_*H_, S_/64), 256, 0, stream>>>(Qa, kv, ksum, attn);

    // 5) output projection -> f32 out
    gemm_bt<0><<<ggrid, 256, 0, stream>>>(attn, wob, bo, nullptr, out, nullptr, M_, E_, E_);
}

// Round 2
// 324.277 us; speedup vs baseline: 1.2636x; 1.2636x over previous
//
#include <hip/hip_runtime.h>
#include <hip/hip_bf16.h>
#include <stdint.h>

#define B_ 4
#define S_ 4096
#define E_ 1024
#define H_ 16
#define D_ 64
#define M_ (B_*S_)          // 16384 rows
constexpr float kEPS = 1e-6f;

typedef unsigned short u16;
typedef unsigned char  u8;
typedef __bf16 bf16x8 __attribute__((ext_vector_type(8)));
typedef float  f32x4  __attribute__((ext_vector_type(4)));
typedef u16    u16x8  __attribute__((ext_vector_type(8)));

typedef const __attribute__((address_space(1))) void* gaddr_t;
typedef __attribute__((address_space(3))) void*       laddr_t;

__device__ __forceinline__ u16 f2bf(float f) {
    union { float f; uint32_t u; } v; v.f = f;
    uint32_t u = v.u;
    u += 0x7fffu + ((u >> 16) & 1u);   // RNE
    return (u16)(u >> 16);
}
__device__ __forceinline__ float bf2f(u16 h) {
    union { uint32_t u; float f; } v; v.u = ((uint32_t)h) << 16;
    return v.f;
}

// ---------------- f32 -> bf16 conversion, 4-wide ----------------
__global__ void cvt_kernel(const float* __restrict__ in, u16* __restrict__ out, int n4) {
    int i = blockIdx.x * blockDim.x + threadIdx.x;
    if (i >= n4) return;
    float4 v = reinterpret_cast<const float4*>(in)[i];
    ushort4 o;
    o.x = f2bf(v.x); o.y = f2bf(v.y); o.z = f2bf(v.z); o.w = f2bf(v.w);
    reinterpret_cast<ushort4*>(out)[i] = o;
}

// ---------------- bf16 GEMM, C = A @ W^T (+bias, epilogue) ----------------
// 256x256 tile, BK=32, 3 LDS buffers, counted-vmcnt 2-ahead pipeline.
// A: [M][K] bf16 row-major. Bw: [N][K] bf16 row-major.
// EPI: 0 = f32 out (bias); 1 = relu(x+b)+eps -> bf16; 2 = EPI1 + mask-zero; 3 = x+b -> bf16
#define BM 256
#define BN 256
#define BK 32
#define NT (E_/BK)          // 32 K-tiles
#define TILE (BM*BK)        // 8192 u16 = 16 KB

template<int EPI>
__global__ __launch_bounds__(512, 2)
void gemm_bt(const u16* __restrict__ A, const u16* __restrict__ Bw,
             const float* __restrict__ bias, const u8* __restrict__ mask,
             float* __restrict__ Cf, u16* __restrict__ Cb)
{
    extern __shared__ u16 lds[];          // 3*TILE A + 3*TILE B = 96 KB
    u16* Asb = lds;
    u16* Bsb = lds + 3*TILE;

    const int tid  = threadIdx.x;
    const int wid  = tid >> 6, lane = tid & 63;
    const int wr   = wid >> 2, wc = wid & 3;      // 2 x 4 waves
    const int n0   = blockIdx.x * BN;
    const int m0   = blockIdx.y * BM;
    const int fr   = lane & 15;                   // fragment row
    const int cg   = lane >> 4;                   // k-chunk group 0..3 (8 elems each)

    // ---- staging geometry: 1024 slots = 256 rows x 4 chunks, 2 slots/thread ----
    const int s0 = tid, s1 = tid + 512;
    const int row0 = s0 >> 2, c0 = s0 & 3;
    const int row1 = s1 >> 2, c1 = s1 & 3;
    // LDS[row][c] holds global chunk (c ^ f(row)), f(row)=(row>>1)&3  (involution)
    const int cc0 = c0 ^ ((row0 >> 1) & 3);
    const int cc1 = c1 ^ ((row1 >> 1) & 3);
    const u16* a0p = A  + (size_t)(m0 + row0)*E_ + cc0*8;
    const u16* a1p = A  + (size_t)(m0 + row1)*E_ + cc1*8;
    const u16* b0p = Bw + (size_t)(n0 + row0)*E_ + cc0*8;
    const u16* b1p = Bw + (size_t)(n0 + row1)*E_ + cc1*8;

    // ---- fragment read offsets (u16 elements), swizzled ----
    const int fsw = (fr >> 1) & 3;
    int aoff[8], boff[4];
#pragma unroll
    for (int mf = 0; mf < 8; ++mf)
        aoff[mf] = (wr*128 + mf*16 + fr)*BK + ((cg ^ fsw) * 8);
#pragma unroll
    for (int nf = 0; nf < 4; ++nf)
        boff[nf] = (wc*64 + nf*16 + fr)*BK + ((cg ^ fsw) * 8);

    f32x4 acc[8][4] = {};

    float bias_v[4];
#pragma unroll
    for (int nf = 0; nf < 4; ++nf) bias_v[nf] = bias[n0 + wc*64 + nf*16 + fr];

    auto STG = [&](int t, int sb) {
        const size_t ke = (size_t)t * BK;
        __builtin_amdgcn_global_load_lds((gaddr_t)(a0p + ke), (laddr_t)(Asb + sb*TILE + s0*8), 16, 0, 0);
        __builtin_amdgcn_global_load_lds((gaddr_t)(a1p + ke), (laddr_t)(Asb + sb*TILE + s1*8), 16, 0, 0);
        __builtin_amdgcn_global_load_lds((gaddr_t)(b0p + ke), (laddr_t)(Bsb + sb*TILE + s0*8), 16, 0, 0);
        __builtin_amdgcn_global_load_lds((gaddr_t)(b1p + ke), (laddr_t)(Bsb + sb*TILE + s1*8), 16, 0, 0);
    };

    auto COMPUTE = [&](int cb) {
        const u16* Ab = Asb + cb*TILE;
        const u16* Bb = Bsb + cb*TILE;
        bf16x8 af[8], bfv[4];
#pragma unroll
        for (int nf = 0; nf < 4; ++nf) bfv[nf] = *reinterpret_cast<const bf16x8*>(Bb + boff[nf]);
#pragma unroll
        for (int mf = 0; mf < 8; ++mf) af[mf]  = *reinterpret_cast<const bf16x8*>(Ab + aoff[mf]);
        asm volatile("s_waitcnt lgkmcnt(0)" ::: "memory");
        __builtin_amdgcn_sched_barrier(0);
        __builtin_amdgcn_s_setprio(1);
#pragma unroll
        for (int mf = 0; mf < 8; ++mf)
#pragma unroll
            for (int nf = 0; nf < 4; ++nf)
                acc[mf][nf] = __builtin_amdgcn_mfma_f32_16x16x32_bf16(af[mf], bfv[nf], acc[mf][nf], 0, 0, 0);
        __builtin_amdgcn_s_setprio(0);
    };

#define W4 do { asm volatile("s_waitcnt vmcnt(4)" ::: "memory"); \
                __builtin_amdgcn_s_barrier(); \
                __builtin_amdgcn_sched_barrier(0); } while (0)
#define W0 do { asm volatile("s_waitcnt vmcnt(0)" ::: "memory"); \
                __builtin_amdgcn_s_barrier(); \
                __builtin_amdgcn_sched_barrier(0); } while (0)

    // prologue: tiles 0,1 into buffers 0,1
    STG(0, 0);
    STG(1, 1);

#pragma unroll 1
    for (int tb = 0; tb < (NT - 2) / 3; ++tb) {   // 10 groups x 3 = tiles 0..29
        const int t = tb * 3;
        W4; STG(t + 2, 2); COMPUTE(0);
        W4; STG(t + 3, 0); COMPUTE(1);
        W4; STG(t + 4, 1); COMPUTE(2);
    }
    W4; COMPUTE(0);    // tile 30
    W0; COMPUTE(1);    // tile 31

    // ---- epilogue ----
#pragma unroll
    for (int mf = 0; mf < 8; ++mf) {
#pragma unroll
        for (int nf = 0; nf < 4; ++nf) {
            const int gn = n0 + wc*64 + nf*16 + fr;
#pragma unroll
            for (int r = 0; r < 4; ++r) {
                const int gm = m0 + wr*128 + mf*16 + cg*4 + r;
                float x = acc[mf][nf][r] + bias_v[nf];
                if (EPI == 0) {
                    Cf[(size_t)gm*E_ + gn] = x;
                } else if (EPI == 1) {
                    x = fmaxf(x, 0.f) + kEPS;
                    Cb[(size_t)gm*E_ + gn] = f2bf(x);
                } else if (EPI == 2) {
                    x = fmaxf(x, 0.f) + kEPS;
                    if (mask[gm]) x = 0.f;
                    Cb[(size_t)gm*E_ + gn] = f2bf(x);
                } else {
                    Cb[(size_t)gm*E_ + gn] = f2bf(x);
                }
            }
        }
    }
}
#undef W4
#undef W0

// ---------------- stage 2: kv partial = K_chunk^T @ V_chunk, ksum partial ----------------
#define SC 128
#define NCHUNK (S_/SC)   // 32
__global__ __launch_bounds__(256)
void kv_partial_kernel(const u16* __restrict__ Ka, const u16* __restrict__ Vv,
                       float* __restrict__ kvp, float* __restrict__ ksp)
{
    __shared__ u16   Ks[SC*64];   // 16 KB
    __shared__ float Vs[SC*64];   // 32 KB
    const int bh = blockIdx.x, b = bh >> 4, h = bh & 15;
    const int s0 = blockIdx.y * SC;
    const int tid = threadIdx.x;

    for (int g = tid; g < SC*8; g += 256) {     // 1024 16B-groups
        int row = g >> 3, c8 = (g & 7) * 8;
        size_t goff = (size_t)(b*S_ + s0 + row)*E_ + h*64 + c8;
        *reinterpret_cast<uint4*>(Ks + row*64 + c8) = *reinterpret_cast<const uint4*>(Ka + goff);
        bf16x8 vv = *reinterpret_cast<const bf16x8*>(Vv + goff);
        f32x4 f0, f1;
#pragma unroll
        for (int j = 0; j < 4; ++j) { f0[j] = (float)vv[j]; f1[j] = (float)vv[4+j]; }
        *reinterpret_cast<f32x4*>(Vs + row*64 + c8)     = f0;
        *reinterpret_cast<f32x4*>(Vs + row*64 + c8 + 4) = f1;
    }
    __syncthreads();

    const int d  = tid >> 2;
    const int v0 = (tid & 3) * 16;
    float acc[16] = {};
    float ks = 0.f;
#pragma unroll 2
    for (int s = 0; s < SC; ++s) {
        float kval = bf2f(Ks[s*64 + d]);
        ks += kval;
        const float* vr = Vs + s*64 + v0;
        f32x4 a0 = *reinterpret_cast<const f32x4*>(vr);
        f32x4 a1 = *reinterpret_cast<const f32x4*>(vr + 4);
        f32x4 a2 = *reinterpret_cast<const f32x4*>(vr + 8);
        f32x4 a3 = *reinterpret_cast<const f32x4*>(vr + 12);
#pragma unroll
        for (int j = 0; j < 4; ++j) {
            acc[j]    += kval * a0[j];
            acc[4+j]  += kval * a1[j];
            acc[8+j]  += kval * a2[j];
            acc[12+j] += kval * a3[j];
        }
    }
    float* dst = kvp + ((size_t)(blockIdx.y*64 + bh)*4096) + d*64 + v0;
#pragma unroll
    for (int j = 0; j < 16; ++j) dst[j] = acc[j];
    if ((tid & 3) == 0) ksp[(size_t)(blockIdx.y*64 + bh)*64 + d] = ks;
}

// ---------------- stage 2b: reduce partials ----------------
__global__ void kv_reduce_kernel(const float* __restrict__ kvp, const float* __restrict__ ksp,
                                 float* __restrict__ kv, float* __restrict__ ksum)
{
    int i = blockIdx.x*256 + threadIdx.x;   // 262144 kv elements
    float s = 0.f;
#pragma unroll
    for (int c = 0; c < NCHUNK; ++c) s += kvp[(size_t)c*262144 + i];
    kv[i] = s;
    if (i < 4096) {
        float t = 0.f;
#pragma unroll
        for (int c = 0; c < NCHUNK; ++c) t += ksp[(size_t)c*4096 + i];
        ksum[i] = t;
    }
}

// ---------------- stage 3: attn = (Qa @ kv) / max(Qa . ksum, eps) ----------------
__global__ __launch_bounds__(256)
void attn_kernel(const u16* __restrict__ Qa, const float* __restrict__ kv,
                 const float* __restrict__ ksum, u16* __restrict__ attn)
{
    __shared__ float kvs[64*64];   // 16 KB
    __shared__ float kss[64];
    const int bh = blockIdx.x, b = bh >> 4, h = bh & 15;
    const int tid = threadIdx.x;
    for (int i = tid; i < 1024; i += 256)
        reinterpret_cast<float4*>(kvs)[i] = reinterpret_cast<const float4*>(kv + (size_t)bh*4096)[i];
    if (tid < 64) kss[tid] = ksum[(size_t)bh*64 + tid];
    __syncthreads();

    const int r  = tid >> 2;             // row within 64-row chunk
    const int v0 = (tid & 3) * 16;
    const int s  = blockIdx.y*64 + r;
    const u16* qrow = Qa + (size_t)(b*S_ + s)*E_ + h*64;

    bf16x8 qv[8];
#pragma unroll
    for (int g = 0; g < 8; ++g) qv[g] = reinterpret_cast<const bf16x8*>(qrow)[g];

    float denom = 0.f;
#pragma unroll
    for (int g = 0; g < 8; ++g)
#pragma unroll
        for (int j = 0; j < 8; ++j) denom += (float)qv[g][j] * kss[g*8 + j];
    denom = fmaxf(denom, kEPS);
    const float inv = 1.0f / denom;

    float acc[16] = {};
#pragma unroll
    for (int g = 0; g < 8; ++g) {
#pragma unroll
        for (int j = 0; j < 8; ++j) {
            const int d = g*8 + j;
            const float qd = (float)qv[g][j];
            const float* kr = kvs + d*64 + v0;
            f32x4 a0 = *reinterpret_cast<const f32x4*>(kr);
            f32x4 a1 = *reinterpret_cast<const f32x4*>(kr + 4);
            f32x4 a2 = *reinterpret_cast<const f32x4*>(kr + 8);
            f32x4 a3 = *reinterpret_cast<const f32x4*>(kr + 12);
#pragma unroll
            for (int v = 0; v < 4; ++v) {
                acc[v]    += qd * a0[v];
                acc[4+v]  += qd * a1[v];
                acc[8+v]  += qd * a2[v];
                acc[12+v] += qd * a3[v];
            }
        }
    }
    u16x8 o0, o1;
#pragma unroll
    for (int j = 0; j < 8; ++j) { o0[j] = f2bf(acc[j]*inv); o1[j] = f2bf(acc[8+j]*inv); }
    u16* orow = attn + (size_t)(b*S_ + s)*E_ + h*64 + v0;
    *reinterpret_cast<u16x8*>(orow)     = o0;
    *reinterpret_cast<u16x8*>(orow + 8) = o1;
}

// ---------------- host ----------------
extern "C" void kernel_launch(void* const* d_in, const int* in_sizes, int n_in,
                              void* d_out, int out_size, void* d_ws, size_t ws_size,
                              hipStream_t stream)
{
    const float* query = (const float*)d_in[0];
    const float* key   = (const float*)d_in[1];
    const float* value = (const float*)d_in[2];
    const u8*    mask  = (const u8*)d_in[3];
    const float* Wq = (const float*)d_in[4];
    const float* bq = (const float*)d_in[5];
    const float* Wk = (const float*)d_in[6];
    const float* bk = (const float*)d_in[7];
    const float* Wv = (const float*)d_in[8];
    const float* bv = (const float*)d_in[9];
    const float* Wo = (const float*)d_in[10];
    const float* bo = (const float*)d_in[11];
    float* out = (float*)d_out;

    const size_t SZ_ME = (size_t)M_ * E_;    // 16,777,216
    const size_t SZ_EE = (size_t)E_ * E_;    // 1,048,576

    char* ws = (char*)d_ws;
    u16* qx  = (u16*)ws; ws += SZ_ME*2;   // query bf16; reused later for attn
    u16* kx  = (u16*)ws; ws += SZ_ME*2;   // key   bf16; reused later for kv partials (32 MiB)
    u16* vx  = (u16*)ws; ws += SZ_ME*2;   // value bf16; reused later for ksp/kv/ksum
    u16* Qa  = (u16*)ws; ws += SZ_ME*2;
    u16* Ka  = (u16*)ws; ws += SZ_ME*2;
    u16* Vv  = (u16*)ws; ws += SZ_ME*2;
    u16* wqb = (u16*)ws; ws += SZ_EE*2;
    u16* wkb = (u16*)ws; ws += SZ_EE*2;
    u16* wvb = (u16*)ws; ws += SZ_EE*2;
    u16* wob = (u16*)ws; ws += SZ_EE*2;

    // overlays (regions free by the time these are written)
    float* kvp  = (float*)kx;                        // 32 chunks * 64 bh * 4096 f32 = 32 MiB
    float* ksp  = (float*)vx;                        // 32*4096 f32 = 512 KiB
    float* kv   = (float*)vx + (size_t)NCHUNK*4096;  // 262144 f32 = 1 MiB
    float* ksum = kv + 262144;                       // 4096 f32
    u16*   attn = qx;

    // 1) conversions to bf16
    cvt_kernel<<<(int)(SZ_ME/4/256), 256, 0, stream>>>(query, qx, (int)(SZ_ME/4));
    cvt_kernel<<<(int)(SZ_ME/4/256), 256, 0, stream>>>(key,   kx, (int)(SZ_ME/4));
    cvt_kernel<<<(int)(SZ_ME/4/256), 256, 0, stream>>>(value, vx, (int)(SZ_ME/4));
    cvt_kernel<<<(int)(SZ_EE/4/256), 256, 0, stream>>>(Wq, wqb, (int)(SZ_EE/4));
    cvt_kernel<<<(int)(SZ_EE/4/256), 256, 0, stream>>>(Wk, wkb, (int)(SZ_EE/4));
    cvt_kernel<<<(int)(SZ_EE/4/256), 256, 0, stream>>>(Wv, wvb, (int)(SZ_EE/4));
    cvt_kernel<<<(int)(SZ_EE/4/256), 256, 0, stream>>>(Wo, wob, (int)(SZ_EE/4));

    // 2) QKV projections (fused epilogues), 256x256 tiles, grid = 4 x 64 = 256 = 1 block/CU
    dim3 ggrid(E_/BN, M_/BM);
    constexpr size_t LDS_BYTES = 6 * TILE * sizeof(u16);   // 96 KB
    gemm_bt<1><<<ggrid, 512, LDS_BYTES, stream>>>(qx, wqb, bq, nullptr, nullptr, Qa);
    gemm_bt<2><<<ggrid, 512, LDS_BYTES, stream>>>(kx, wkb, bk, mask,    nullptr, Ka);
    gemm_bt<3><<<ggrid, 512, LDS_BYTES, stream>>>(vx, wvb, bv, nullptr, nullptr, Vv);

    // 3) kv_context + k_sum (two-phase, deterministic)
    kv_partial_kernel<<<dim3(B_*H_, NCHUNK), 256, 0, stream>>>(Ka, Vv, kvp, ksp);
    kv_reduce_kernel<<<1024, 256, 0, stream>>>(kvp, ksp, kv, ksum);

    // 4) attn numerator / denom
    attn_kernel<<<dim3(B_*H_, S_/64), 256, 0, stream>>>(Qa, kv, ksum, attn);

    // 5) output projection -> f32 out
    gemm_bt<0><<<ggrid, 512, LDS_BYTES, stream>>>(attn, wob, bo, nullptr, out, nullptr);
}